// Round 2
// baseline (185.064 us; speedup 1.0000x reference)
//
#include <hip/hip_runtime.h>

// MechanisticNRTLLoss — B=1e6 samples, scalar fp32 loss.
// R11: 2 samples per thread.
//  - Pair loads are wide & contiguous: pred/target = 3x dwordx4 (16B aligned),
//    g = 9x dwordx2, dirs/noise = dwordx2 runs. ~34 loads + half the address
//    math per pair (vs 46 scalar loads for 2 threads before).
//  - Two fully independent per-sample computations interleave in one basic
//    block -> 2x ILP hides trans-op and L2/L3 load latency.
//  - __launch_bounds__(256,3) (~168 VGPRs): R10's (256,4)=128-reg cap is the
//    suspected reason staging didn't pay; pairing needs ~150 live regs.

constexpr float ALPHA    = 0.3f;
constexpr float R_GAS    = 8.314462618f;
constexpr float EPS      = 1e-12f;
constexpr float TAU_CLIP = 10.0f;
constexpr float LN_CLIP  = 20.0f;
constexpr float EPS_FD   = 1e-4f;

constexpr float LOG2E = 1.44269504088896340736f;
constexpr float LN2   = 0.69314718055994530942f;

typedef float v2f __attribute__((ext_vector_type(2)));
typedef float v4f __attribute__((ext_vector_type(4)));

__device__ __forceinline__ float clipf(float v, float lo, float hi) {
    return fminf(fmaxf(v, lo), hi);
}
__device__ __forceinline__ float fast_rcp(float x) { return __builtin_amdgcn_rcpf(x); }
__device__ __forceinline__ v2f nt_load2(const float* p) {
    return __builtin_nontemporal_load((const v2f*)p);
}
__device__ __forceinline__ v4f nt_load4(const float* p) {
    return __builtin_nontemporal_load((const v4f*)p);
}
__device__ __forceinline__ float nt_load(const float* p) {
    return __builtin_nontemporal_load(p);
}

struct Mats {
    float tau[3][3];
    float G[3][3];
    float tG[3][3];
};

// per-sample staged inputs (40 floats)
struct SIn {
    float p[6];
    float t[6];
    float T;
    float g[9];
    float dv[2][3];
    float nv[4][3];
};

// ln_gamma for a 3-component system.
//   term2_ij = c_j*(tG_ij - G_ij*ratio_j),  c_j = x_j*invd_j   (2 FMA per term)
__device__ __forceinline__ void ln_gamma3(const float x[3], const Mats& M, float lg[3]) {
    float ratio[3], c[3];
#pragma unroll
    for (int i = 0; i < 3; ++i) {
        float d = x[0] * M.G[0][i] + x[1] * M.G[1][i] + x[2] * M.G[2][i];
        d = fmaxf(d, EPS);
        float A = x[0] * M.tG[0][i] + x[1] * M.tG[1][i] + x[2] * M.tG[2][i];
        float inv = fast_rcp(d);
        ratio[i] = A * inv;
        c[i] = x[i] * inv;
    }
#pragma unroll
    for (int i = 0; i < 3; ++i) {
        float s = ratio[i];
#pragma unroll
        for (int j = 0; j < 3; ++j) {
            s += c[j] * (M.tG[i][j] - M.G[i][j] * ratio[j]);
        }
        lg[i] = clipf(s, -LN_CLIP, LN_CLIP);
    }
}

__device__ __forceinline__ void renorm3(float x[3]) {
    x[0] = fmaxf(x[0], 0.0f);
    x[1] = fmaxf(x[1], 0.0f);
    x[2] = fmaxf(x[2], 0.0f);
    float inv = fast_rcp(fmaxf(x[0] + x[1] + x[2], EPS));
    x[0] *= inv; x[1] *= inv; x[2] *= inv;
}

// full per-sample loss term: sup/6 + phy/3 + 0.05*gd + 0.025*tpd
__device__ __forceinline__ float sample_contrib(const SIn& in) {
    float sup;
    {
        float d0 = in.p[0] - in.t[0], d1 = in.p[1] - in.t[1];
        float d2 = in.p[2] - in.t[2], d3 = in.p[3] - in.t[3];
        float d4 = in.p[4] - in.t[4], d5 = in.p[5] - in.t[5];
        sup = d0 * d0 + d1 * d1 + d2 * d2 + d3 * d3 + d4 * d4 + d5 * d5;
    }

    float xE[3] = {in.p[0], in.p[1], in.p[2]};
    float xR[3] = {in.p[3], in.p[4], in.p[5]};
    renorm3(xE);
    renorm3(xR);

    const float Tc = fmaxf(in.T, 1.0f);
    const float invRT = fast_rcp(R_GAS * Tc);
    Mats M;
#pragma unroll
    for (int a = 0; a < 3; ++a) {
#pragma unroll
        for (int b = 0; b < 3; ++b) {
            float ta = clipf(in.g[a * 3 + b] * invRT, -TAU_CLIP, TAU_CLIP);
            float Gv = __builtin_amdgcn_exp2f((-ALPHA * LOG2E) * ta);
            M.tau[a][b] = ta;
            M.G[a][b]   = Gv;
            M.tG[a][b]  = ta * Gv;
        }
    }

    float lgE[3], lgR[3];
    ln_gamma3(xE, M, lgE);
    ln_gamma3(xR, M, lgR);

    float logxE[3];
    float phy = 0.0f;
#pragma unroll
    for (int k = 0; k < 3; ++k) {
        logxE[k] = LN2 * __builtin_amdgcn_logf(fmaxf(xE[k], EPS));
        float logxR = LN2 * __builtin_amdgcn_logf(fmaxf(xR[k], EPS));
        float r = logxE[k] + lgE[k] - logxR - lgR[k];
        phy += r * r;
    }

    float gdsum = 0.0f;
#pragma unroll
    for (int d = 0; d < 2; ++d) {
        float xp[3], xm[3];
#pragma unroll
        for (int k = 0; k < 3; ++k) {
            xp[k] = xE[k] + EPS_FD * in.dv[d][k];
            xm[k] = xE[k] - EPS_FD * in.dv[d][k];
        }
        renorm3(xp);
        renorm3(xm);
        float lgp[3], lgm[3];
        ln_gamma3(xp, M, lgp);
        ln_gamma3(xm, M, lgm);
        float gd = 0.0f;
#pragma unroll
        for (int k = 0; k < 3; ++k) gd += xE[k] * (lgp[k] - lgm[k]);
        gd *= 0.5f / EPS_FD;
        gdsum += gd * gd;
    }

    float base[3];
#pragma unroll
    for (int k = 0; k < 3; ++k) base[k] = logxE[k] + lgE[k];

    float tpdsum = 0.0f;
#pragma unroll
    for (int tr = 0; tr < 4; ++tr) {
        float w[3];
#pragma unroll
        for (int k = 0; k < 3; ++k) w[k] = xE[k] + in.nv[tr][k];
        renorm3(w);
        float lgw[3];
        ln_gamma3(w, M, lgw);
        float tpd = 0.0f;
#pragma unroll
        for (int k = 0; k < 3; ++k) {
            float logw = LN2 * __builtin_amdgcn_logf(fmaxf(w[k], EPS));
            tpd += w[k] * (logw + lgw[k] - base[k]);
        }
        tpdsum += fmaxf(-tpd, 0.0f);  // MARGIN = 0
    }

    return sup * (1.0f / 6.0f)
         + phy * (1.0f / 3.0f)
         + 0.05f * gdsum
         + 0.025f * tpdsum;
}

__global__ __launch_bounds__(256, 3) void nrtl_loss_kernel(
    const float* __restrict__ pred,   // (B,6)
    const float* __restrict__ target, // (B,6)
    const float* __restrict__ Tarr,   // (B,)
    const float* __restrict__ g,      // (B,3,3)
    const float* __restrict__ dirs,   // (2,B,3)
    const float* __restrict__ noise,  // (4,B,3)
    float* __restrict__ partials, int B)
{
    const int t  = blockIdx.x * blockDim.x + threadIdx.x;
    const int i0 = t * 2;
    float contrib = 0.0f;

    if (i0 + 1 < B) {
        // ---------------- pair-wide staged loads ----------------
        SIn in[2];

        {   // pred: 12 contiguous floats, 16B aligned (48B pair stride)
            const float* prow = pred + (size_t)i0 * 6;
            v4f P0 = nt_load4(prow);
            v4f P1 = nt_load4(prow + 4);
            v4f P2 = nt_load4(prow + 8);
            in[0].p[0]=P0.x; in[0].p[1]=P0.y; in[0].p[2]=P0.z; in[0].p[3]=P0.w;
            in[0].p[4]=P1.x; in[0].p[5]=P1.y;
            in[1].p[0]=P1.z; in[1].p[1]=P1.w;
            in[1].p[2]=P2.x; in[1].p[3]=P2.y; in[1].p[4]=P2.z; in[1].p[5]=P2.w;
        }
        {   // target: same layout
            const float* trow = target + (size_t)i0 * 6;
            v4f T0 = nt_load4(trow);
            v4f T1 = nt_load4(trow + 4);
            v4f T2 = nt_load4(trow + 8);
            in[0].t[0]=T0.x; in[0].t[1]=T0.y; in[0].t[2]=T0.z; in[0].t[3]=T0.w;
            in[0].t[4]=T1.x; in[0].t[5]=T1.y;
            in[1].t[0]=T1.z; in[1].t[1]=T1.w;
            in[1].t[2]=T2.x; in[1].t[3]=T2.y; in[1].t[4]=T2.z; in[1].t[5]=T2.w;
        }
        {   // T: 2 contiguous floats, 8B aligned
            v2f Tv = nt_load2(Tarr + i0);
            in[0].T = Tv.x; in[1].T = Tv.y;
        }
        {   // g: 18 contiguous floats; pair stride 72B -> only 8B aligned -> 9x dwordx2
            const float* grow = g + (size_t)i0 * 9;
            float gg[18];
#pragma unroll
            for (int j = 0; j < 9; ++j) {
                v2f gv = nt_load2(grow + 2 * j);
                gg[2 * j]     = gv.x;
                gg[2 * j + 1] = gv.y;
            }
#pragma unroll
            for (int k = 0; k < 9; ++k) { in[0].g[k] = gg[k]; in[1].g[k] = gg[9 + k]; }
        }
#pragma unroll
        for (int d = 0; d < 2; ++d) {   // dirs: 6 contiguous floats per d, 8B aligned
            const float* drow = dirs + ((size_t)d * B + i0) * 3;
            v2f a = nt_load2(drow);
            v2f b = nt_load2(drow + 2);
            v2f c = nt_load2(drow + 4);
            in[0].dv[d][0]=a.x; in[0].dv[d][1]=a.y; in[0].dv[d][2]=b.x;
            in[1].dv[d][0]=b.y; in[1].dv[d][1]=c.x; in[1].dv[d][2]=c.y;
        }
#pragma unroll
        for (int tr = 0; tr < 4; ++tr) {  // noise: 6 contiguous floats per trial
            const float* nrow = noise + ((size_t)tr * B + i0) * 3;
            v2f a = nt_load2(nrow);
            v2f b = nt_load2(nrow + 2);
            v2f c = nt_load2(nrow + 4);
            in[0].nv[tr][0]=a.x; in[0].nv[tr][1]=a.y; in[0].nv[tr][2]=b.x;
            in[1].nv[tr][0]=b.y; in[1].nv[tr][1]=c.x; in[1].nv[tr][2]=c.y;
        }

        // ---------------- two independent compute chains ----------------
        contrib = sample_contrib(in[0]) + sample_contrib(in[1]);
        contrib *= 1.0f / (float)B;
    } else if (i0 < B) {
        // odd-B tail: scalar path for the final lone sample (cold)
        SIn in;
        const float* prow = pred   + (size_t)i0 * 6;
        const float* trow = target + (size_t)i0 * 6;
        const float* grow = g      + (size_t)i0 * 9;
#pragma unroll
        for (int k = 0; k < 6; ++k) { in.p[k] = nt_load(prow + k); in.t[k] = nt_load(trow + k); }
        in.T = nt_load(Tarr + i0);
#pragma unroll
        for (int k = 0; k < 9; ++k) in.g[k] = nt_load(grow + k);
#pragma unroll
        for (int d = 0; d < 2; ++d) {
            const float* drow = dirs + ((size_t)d * B + i0) * 3;
#pragma unroll
            for (int k = 0; k < 3; ++k) in.dv[d][k] = nt_load(drow + k);
        }
#pragma unroll
        for (int tr = 0; tr < 4; ++tr) {
            const float* nrow = noise + ((size_t)tr * B + i0) * 3;
#pragma unroll
            for (int k = 0; k < 3; ++k) in.nv[tr][k] = nt_load(nrow + k);
        }
        contrib = sample_contrib(in) * (1.0f / (float)B);
    }

    // ---- block reduction: wave shuffle then LDS across 4 waves ----
#pragma unroll
    for (int off = 32; off > 0; off >>= 1)
        contrib += __shfl_down(contrib, off, 64);

    __shared__ float ssum[4];
    const int lane = threadIdx.x & 63;
    const int wid  = threadIdx.x >> 6;
    if (lane == 0) ssum[wid] = contrib;
    __syncthreads();
    if (threadIdx.x == 0) {
        partials[blockIdx.x] = ssum[0] + ssum[1] + ssum[2] + ssum[3];
    }
}

__global__ __launch_bounds__(256) void reduce_kernel(
    const float* __restrict__ partials, int n, float* __restrict__ out)
{
    double sacc = 0.0;
    for (int j = threadIdx.x; j < n; j += 256) sacc += (double)partials[j];
#pragma unroll
    for (int off = 32; off > 0; off >>= 1)
        sacc += __shfl_down(sacc, off, 64);
    __shared__ double ds[4];
    const int lane = threadIdx.x & 63;
    const int wid  = threadIdx.x >> 6;
    if (lane == 0) ds[wid] = sacc;
    __syncthreads();
    if (threadIdx.x == 0) out[0] = (float)(ds[0] + ds[1] + ds[2] + ds[3]);
}

extern "C" void kernel_launch(void* const* d_in, const int* in_sizes, int n_in,
                              void* d_out, int out_size, void* d_ws, size_t ws_size,
                              hipStream_t stream) {
    const float* pred   = (const float*)d_in[0];
    const float* target = (const float*)d_in[1];
    const float* Tarr   = (const float*)d_in[2];
    const float* g      = (const float*)d_in[3];
    const float* dirs   = (const float*)d_in[4];
    const float* noise  = (const float*)d_in[5];
    const int B = in_sizes[2];  // T is (B,)

    float* partials = (float*)d_ws;
    float* out      = (float*)d_out;

    const int block   = 256;
    const int pairs   = (B + 1) / 2;
    const int grid    = (pairs + block - 1) / block;
    nrtl_loss_kernel<<<grid, block, 0, stream>>>(pred, target, Tarr, g, dirs, noise, partials, B);
    reduce_kernel<<<1, block, 0, stream>>>(partials, grid, out);
}

// Round 4
// 167.183 us; speedup vs baseline: 1.1070x; 1.1070x over previous
//
#include <hip/hip_runtime.h>

// MechanisticNRTLLoss — B=1e6 samples, scalar fp32 loss.
// R13 = R12 resubmitted (round-3 bench was an infra failure, no data).
// 1 sample/thread (R9/R10 structure) + FORCED load staging.
//  - All 34 input loads issue first; __builtin_amdgcn_sched_barrier(0) pins
//    them above the math so the compiler cannot sink them back to their uses
//    (which is what neutered R10). All load latencies overlap once instead of
//    serializing in register-starved batches (R9: VGPR=48 -> ~8 round trips).
//  - Loads issued in first-use order (pred,target,T,g,dirs,noise) so partial
//    vmcnt(N) waits let early math start while later loads are in flight.
//  - __launch_bounds__(256,3): ~168-reg headroom, no spill; expected VGPR
//    ~100-120 still gives 4 waves/SIMD in hardware.
//  - Keeps R10's strength-reduced ln_gamma3 (c_j*(tG - G*ratio), 2 FMA/term).

constexpr float ALPHA    = 0.3f;
constexpr float R_GAS    = 8.314462618f;
constexpr float EPS      = 1e-12f;
constexpr float TAU_CLIP = 10.0f;
constexpr float LN_CLIP  = 20.0f;
constexpr float EPS_FD   = 1e-4f;

constexpr float LOG2E = 1.44269504088896340736f;
constexpr float LN2   = 0.69314718055994530942f;

typedef float v2f __attribute__((ext_vector_type(2)));

__device__ __forceinline__ float clipf(float v, float lo, float hi) {
    return fminf(fmaxf(v, lo), hi);
}
__device__ __forceinline__ float fast_rcp(float x) { return __builtin_amdgcn_rcpf(x); }
__device__ __forceinline__ v2f nt_load2(const float* p) {
    return __builtin_nontemporal_load((const v2f*)p);
}
__device__ __forceinline__ float nt_load(const float* p) {
    return __builtin_nontemporal_load(p);
}

struct Mats {
    float tau[3][3];
    float G[3][3];
    float tG[3][3];
};

// ln_gamma for a 3-component system.
//   term2_ij = c_j*(tG_ij - G_ij*ratio_j),  c_j = x_j*invd_j   (2 FMA per term)
__device__ __forceinline__ void ln_gamma3(const float x[3], const Mats& M, float lg[3]) {
    float ratio[3], c[3];
#pragma unroll
    for (int i = 0; i < 3; ++i) {
        float d = x[0] * M.G[0][i] + x[1] * M.G[1][i] + x[2] * M.G[2][i];
        d = fmaxf(d, EPS);
        float A = x[0] * M.tG[0][i] + x[1] * M.tG[1][i] + x[2] * M.tG[2][i];
        float inv = fast_rcp(d);
        ratio[i] = A * inv;
        c[i] = x[i] * inv;
    }
#pragma unroll
    for (int i = 0; i < 3; ++i) {
        float s = ratio[i];
#pragma unroll
        for (int j = 0; j < 3; ++j) {
            s += c[j] * (M.tG[i][j] - M.G[i][j] * ratio[j]);
        }
        lg[i] = clipf(s, -LN_CLIP, LN_CLIP);
    }
}

__device__ __forceinline__ void renorm3(float x[3]) {
    x[0] = fmaxf(x[0], 0.0f);
    x[1] = fmaxf(x[1], 0.0f);
    x[2] = fmaxf(x[2], 0.0f);
    float inv = fast_rcp(fmaxf(x[0] + x[1] + x[2], EPS));
    x[0] *= inv; x[1] *= inv; x[2] *= inv;
}

__global__ __launch_bounds__(256, 3) void nrtl_loss_kernel(
    const float* __restrict__ pred,   // (B,6)
    const float* __restrict__ target, // (B,6)
    const float* __restrict__ Tarr,   // (B,)
    const float* __restrict__ g,      // (B,3,3)
    const float* __restrict__ dirs,   // (2,B,3)
    const float* __restrict__ noise,  // (4,B,3)
    float* __restrict__ partials, int B)
{
    const int i = blockIdx.x * blockDim.x + threadIdx.x;
    float contrib = 0.0f;

    if (i < B) {
        const float* prow = pred   + (size_t)i * 6;
        const float* trow = target + (size_t)i * 6;
        const float* grow = g      + (size_t)i * 9;

        // ============== stage ALL inputs, in first-use order ==============
        v2f p01 = nt_load2(prow);
        v2f p23 = nt_load2(prow + 2);
        v2f p45 = nt_load2(prow + 4);
        v2f t01 = nt_load2(trow);
        v2f t23 = nt_load2(trow + 2);
        v2f t45 = nt_load2(trow + 4);
        float Tv = nt_load(Tarr + i);
        float gv[9];
#pragma unroll
        for (int k = 0; k < 9; ++k) gv[k] = nt_load(grow + k);
        float dv[2][3];
#pragma unroll
        for (int d = 0; d < 2; ++d) {
            const float* drow = dirs + ((size_t)d * B + i) * 3;
#pragma unroll
            for (int k = 0; k < 3; ++k) dv[d][k] = nt_load(drow + k);
        }
        float nv[4][3];
#pragma unroll
        for (int tr = 0; tr < 4; ++tr) {
            const float* nrow = noise + ((size_t)tr * B + i) * 3;
#pragma unroll
            for (int k = 0; k < 3; ++k) nv[tr][k] = nt_load(nrow + k);
        }
        // Pin: nothing below may be hoisted above, no load may sink below.
        __builtin_amdgcn_sched_barrier(0);

        // ========================== compute ================================
        float sup;
        {
            float d0 = p01.x - t01.x, d1 = p01.y - t01.y;
            float d2 = p23.x - t23.x, d3 = p23.y - t23.y;
            float d4 = p45.x - t45.x, d5 = p45.y - t45.y;
            sup = d0 * d0 + d1 * d1 + d2 * d2 + d3 * d3 + d4 * d4 + d5 * d5;
        }

        float xE[3] = {p01.x, p01.y, p23.x};
        float xR[3] = {p23.y, p45.x, p45.y};
        renorm3(xE);
        renorm3(xR);

        const float Tc = fmaxf(Tv, 1.0f);
        const float invRT = fast_rcp(R_GAS * Tc);
        Mats M;
#pragma unroll
        for (int a = 0; a < 3; ++a) {
#pragma unroll
            for (int b = 0; b < 3; ++b) {
                float ta = clipf(gv[a * 3 + b] * invRT, -TAU_CLIP, TAU_CLIP);
                float Gv = __builtin_amdgcn_exp2f((-ALPHA * LOG2E) * ta);
                M.tau[a][b] = ta;
                M.G[a][b]   = Gv;
                M.tG[a][b]  = ta * Gv;
            }
        }

        float lgE[3], lgR[3];
        ln_gamma3(xE, M, lgE);
        ln_gamma3(xR, M, lgR);

        float logxE[3];
        float phy = 0.0f;
#pragma unroll
        for (int k = 0; k < 3; ++k) {
            logxE[k] = LN2 * __builtin_amdgcn_logf(fmaxf(xE[k], EPS));
            float logxR = LN2 * __builtin_amdgcn_logf(fmaxf(xR[k], EPS));
            float r = logxE[k] + lgE[k] - logxR - lgR[k];
            phy += r * r;
        }

        float gdsum = 0.0f;
#pragma unroll
        for (int d = 0; d < 2; ++d) {
            float xp[3], xm[3];
#pragma unroll
            for (int k = 0; k < 3; ++k) {
                xp[k] = xE[k] + EPS_FD * dv[d][k];
                xm[k] = xE[k] - EPS_FD * dv[d][k];
            }
            renorm3(xp);
            renorm3(xm);
            float lgp[3], lgm[3];
            ln_gamma3(xp, M, lgp);
            ln_gamma3(xm, M, lgm);
            float gd = 0.0f;
#pragma unroll
            for (int k = 0; k < 3; ++k) gd += xE[k] * (lgp[k] - lgm[k]);
            gd *= 0.5f / EPS_FD;
            gdsum += gd * gd;
        }

        // TPD: hoist the per-sample base ln(xE)+lgE out of the trial loop.
        float base[3];
#pragma unroll
        for (int k = 0; k < 3; ++k) base[k] = logxE[k] + lgE[k];

        float tpdsum = 0.0f;
#pragma unroll
        for (int tr = 0; tr < 4; ++tr) {
            float w[3];
#pragma unroll
            for (int k = 0; k < 3; ++k) w[k] = xE[k] + nv[tr][k];
            renorm3(w);
            float lgw[3];
            ln_gamma3(w, M, lgw);
            float tpd = 0.0f;
#pragma unroll
            for (int k = 0; k < 3; ++k) {
                float logw = LN2 * __builtin_amdgcn_logf(fmaxf(w[k], EPS));
                tpd += w[k] * (logw + lgw[k] - base[k]);
            }
            tpdsum += fmaxf(-tpd, 0.0f);  // MARGIN = 0
        }

        const float invB = 1.0f / (float)B;
        contrib = invB * (sup * (1.0f / 6.0f)
                          + phy * (1.0f / 3.0f)
                          + 0.05f * gdsum
                          + 0.025f * tpdsum);
    }

    // ---- block reduction: wave shuffle then LDS across 4 waves ----
#pragma unroll
    for (int off = 32; off > 0; off >>= 1)
        contrib += __shfl_down(contrib, off, 64);

    __shared__ float ssum[4];
    const int lane = threadIdx.x & 63;
    const int wid  = threadIdx.x >> 6;
    if (lane == 0) ssum[wid] = contrib;
    __syncthreads();
    if (threadIdx.x == 0) {
        partials[blockIdx.x] = ssum[0] + ssum[1] + ssum[2] + ssum[3];
    }
}

__global__ __launch_bounds__(256) void reduce_kernel(
    const float* __restrict__ partials, int n, float* __restrict__ out)
{
    double sacc = 0.0;
    for (int j = threadIdx.x; j < n; j += 256) sacc += (double)partials[j];
#pragma unroll
    for (int off = 32; off > 0; off >>= 1)
        sacc += __shfl_down(sacc, off, 64);
    __shared__ double ds[4];
    const int lane = threadIdx.x & 63;
    const int wid  = threadIdx.x >> 6;
    if (lane == 0) ds[wid] = sacc;
    __syncthreads();
    if (threadIdx.x == 0) out[0] = (float)(ds[0] + ds[1] + ds[2] + ds[3]);
}

extern "C" void kernel_launch(void* const* d_in, const int* in_sizes, int n_in,
                              void* d_out, int out_size, void* d_ws, size_t ws_size,
                              hipStream_t stream) {
    const float* pred   = (const float*)d_in[0];
    const float* target = (const float*)d_in[1];
    const float* Tarr   = (const float*)d_in[2];
    const float* g      = (const float*)d_in[3];
    const float* dirs   = (const float*)d_in[4];
    const float* noise  = (const float*)d_in[5];
    const int B = in_sizes[2];  // T is (B,)

    float* partials = (float*)d_ws;
    float* out      = (float*)d_out;

    const int block = 256;
    const int grid  = (B + block - 1) / block;
    nrtl_loss_kernel<<<grid, block, 0, stream>>>(pred, target, Tarr, g, dirs, noise, partials, B);
    reduce_kernel<<<1, block, 0, stream>>>(partials, grid, out);
}